// Round 4
// baseline (313.740 us; speedup 1.0000x reference)
//
#include <hip/hip_runtime.h>
#include <math.h>

#define BB 16
#define TT 144
#define TP1 145
#define HWP 16384
#define HW4 4096   // f4/h4 groups per image
#define HW8 2048   // f8/h8 groups per image
#define LL 6
#define BIGE 1e30

typedef float     f4 __attribute__((ext_vector_type(4)));
typedef float     f8 __attribute__((ext_vector_type(8)));
typedef _Float16  h4 __attribute__((ext_vector_type(4)));
typedef _Float16  h8 __attribute__((ext_vector_type(8)));

// ---- workspace layout (bytes) ----
static const size_t OFF_A     = 0;                  // B*HW f32 (1 MB)
static const size_t OFF_M     = 1u << 20;
static const size_t OFF_U     = 2u << 20;
static const size_t OFF_V     = 3u << 20;
static const size_t OFF_ERR32 = 4u << 20;           // B*145 f64
static const size_t OFF_ERR16 = (4u << 20) + 32768; // B*145 f64 (screening scores)
static const size_t OFF_D     = (4u << 20) + 65536; // B f64 (error-bound accumulator)
static const size_t OFF_USED  = (4u << 20) + 81920; // B*145 i32
static const size_t OFF_B16   = (4u << 20) + 98304; // B*T*HW fp16 = 75,497,472
static const size_t WS_FULL   = OFF_B16 + 75497472ull;

__device__ __forceinline__ float hsum(f4 v) { return ((v.x + v.y) + v.z) + v.w; }
__device__ __forceinline__ float hsum8(f8 v) {
    return (((v.s0 + v.s1) + (v.s2 + v.s3)) + ((v.s4 + v.s5) + (v.s6 + v.s7)));
}

__device__ __forceinline__ double blk_reduce(double s) {
    for (int off = 32; off; off >>= 1) s += __shfl_down(s, off);
    __shared__ double smr[4];
    if ((threadIdx.x & 63) == 0) smr[threadIdx.x >> 6] = s;
    __syncthreads();
    return smr[0] + smr[1] + smr[2] + smr[3];
}

__device__ __forceinline__ void blk_reduce2(double& a, double& b) {
    for (int off = 32; off; off >>= 1) { a += __shfl_down(a, off); b += __shfl_down(b, off); }
    __shared__ double sa[4], sb[4];
    if ((threadIdx.x & 63) == 0) { sa[threadIdx.x >> 6] = a; sb[threadIdx.x >> 6] = b; }
    __syncthreads();
    a = sa[0] + sa[1] + sa[2] + sa[3];
    b = sb[0] + sb[1] + sb[2] + sb[3];
}

// Materialize below16 = fp16(t*m + bg*(1-m)), compute EXACT step-0 errors in f32/f64
// (from the in-register f32 w), zero used[]. temps/masks read-once -> non-temporal.
__global__ void k_below_err0(const f4* __restrict__ temps, const f4* __restrict__ masks,
                             const f4* __restrict__ bg, const f4* __restrict__ x,
                             h4* __restrict__ below16, double* __restrict__ err32,
                             int* __restrict__ used) {
    const int t = blockIdx.x, b = blockIdx.y, tid = threadIdx.x;
    const f4* xb = x + (size_t)b * HW4;
    double s = 0.0;
    if (t == 0) {
        if (tid < TP1) used[b * TP1 + tid] = 0;
        for (int j = tid; j < HW4; j += 256) {
            f4 xv = xb[j];
            s += (double)(100.f - 10.f * hsum(xv));
        }
    } else {
        const size_t row = ((size_t)(b * TT + t - 1)) * HW4;
        for (int j = tid; j < HW4; j += 256) {
            f4 tv = __builtin_nontemporal_load(&temps[row + j]);
            f4 mv = __builtin_nontemporal_load(&masks[row + j]);
            f4 bv = bg[j], xv = xb[j];
            f4 w = tv * mv + bv * (1.f - mv);
            below16[row + j] = __builtin_convertvector(w, h4);
            f4 g = w * (w - 2.f * xv);
            s += (double)hsum(g);
        }
    }
    double tot = blk_reduce(s);
    if (tid == 0) err32[b * TP1 + t] = tot;
}

// Screening pass: err16[b][t] = sum_p(v*w16^2 - 2*u*w16); t==0 exact + D_b = sum(v+|u|).
__global__ void k_err16(const h8* __restrict__ below16,
                        const f4* __restrict__ u4, const f4* __restrict__ v4,
                        const int* __restrict__ used, double* __restrict__ err16,
                        double* __restrict__ D) {
    const int t = blockIdx.x, b = blockIdx.y, tid = threadIdx.x;
    if (t != 0 && used[b * TP1 + t]) {
        if (tid == 0) err16[b * TP1 + t] = BIGE;
        return;
    }
    if (t == 0) {
        const f4* ub = u4 + (size_t)b * HW4;
        const f4* vb = v4 + (size_t)b * HW4;
        double s = 0.0, d = 0.0;
        for (int j = tid; j < HW4; j += 256) {
            f4 uu = ub[j], vv = vb[j];
            s += (double)(25.f * hsum(vv) - 10.f * hsum(uu));
            f4 au = {fabsf(uu.x), fabsf(uu.y), fabsf(uu.z), fabsf(uu.w)};
            d += (double)hsum(vv + au);
        }
        blk_reduce2(s, d);
        if (tid == 0) { err16[b * TP1] = s; D[b] = d; }
        return;
    }
    const f8* ub = (const f8*)(u4 + (size_t)b * HW4);
    const f8* vb = (const f8*)(v4 + (size_t)b * HW4);
    const h8* wb = below16 + ((size_t)(b * TT + t - 1)) * HW8;
    double s = 0.0;
    for (int j = tid; j < HW8; j += 256) {
        f8 w = __builtin_convertvector(wb[j], f8);
        f8 uu = ub[j], vv = vb[j];
        f8 g = w * (vv * w - 2.f * uu);
        s += (double)hsum8(g);
    }
    double tot = blk_reduce(s);
    if (tid == 0) err16[b * TP1 + t] = tot;
}

// Sound refine: any t with err16 within margin of min16 gets an exact f32 re-eval
// (recompute w from temps/masks — same arithmetic as the passing f32 path); others -> BIGE.
__global__ void k_refine(const f4* __restrict__ temps, const f4* __restrict__ masks,
                         const f4* __restrict__ bg,
                         const f4* __restrict__ u4, const f4* __restrict__ v4,
                         const double* __restrict__ err16, const double* __restrict__ D,
                         double* __restrict__ err32) {
    const int t = blockIdx.x, b = blockIdx.y, tid = threadIdx.x;
    // block-wide min of err16[b][:]
    double e = (tid < TP1) ? err16[b * TP1 + tid] : 1e300;
    for (int off = 32; off; off >>= 1) {
        double oe = __shfl_down(e, off);
        e = (oe < e) ? oe : e;
    }
    __shared__ double sm[4];
    __shared__ double smin_s;
    if ((tid & 63) == 0) sm[tid >> 6] = e;
    __syncthreads();
    if (tid == 0) {
        double m0 = (sm[0] < sm[1]) ? sm[0] : sm[1];
        double m1 = (sm[2] < sm[3]) ? sm[2] : sm[3];
        smin_s = (m0 < m1) ? m0 : m1;
    }
    __syncthreads();
    const double smin = smin_s;
    const double mine = err16[b * TP1 + t];
    const double margin = 2.0 * (1.0e-3 * D[b] + 0.25);
    if (mine > smin + margin) {               // provably not the argmin
        if (tid == 0) err32[b * TP1 + t] = BIGE;
        return;
    }
    if (t == 0) {                              // already exact
        if (tid == 0) err32[b * TP1 + t] = mine;
        return;
    }
    const f4* ub = u4 + (size_t)b * HW4;
    const f4* vb = v4 + (size_t)b * HW4;
    const size_t row = ((size_t)(b * TT + t - 1)) * HW4;
    double s = 0.0;
    for (int j = tid; j < HW4; j += 256) {
        f4 tv = temps[row + j], mv = masks[row + j], bv = bg[j];
        f4 uu = ub[j], vv = vb[j];
        f4 w = tv * mv + bv * (1.f - mv);
        f4 g = w * (vv * w - 2.f * uu);
        s += (double)hsum(g);
    }
    double tot = blk_reduce(s);
    if (tid == 0) err32[b * TP1 + t] = tot;
}

// Fallback (small ws): exact f32 err with on-the-fly w.
__global__ void k_err_f32(const f4* __restrict__ temps, const f4* __restrict__ masks,
                          const f4* __restrict__ bg,
                          const f4* __restrict__ u4, const f4* __restrict__ v4,
                          const int* __restrict__ used, double* __restrict__ err32) {
    const int t = blockIdx.x, b = blockIdx.y, tid = threadIdx.x;
    if (t != 0 && used[b * TP1 + t]) {
        if (tid == 0) err32[b * TP1 + t] = BIGE;
        return;
    }
    const f4* ub = u4 + (size_t)b * HW4;
    const f4* vb = v4 + (size_t)b * HW4;
    double s = 0.0;
    if (t == 0) {
        for (int j = tid; j < HW4; j += 256) {
            f4 uu = ub[j], vv = vb[j];
            s += (double)(25.f * hsum(vv) - 10.f * hsum(uu));
        }
    } else {
        const size_t row = ((size_t)(b * TT + t - 1)) * HW4;
        for (int j = tid; j < HW4; j += 256) {
            f4 tv = temps[row + j], mv = masks[row + j], bv = bg[j];
            f4 uu = ub[j], vv = vb[j];
            f4 w = tv * mv + bv * (1.f - mv);
            f4 g = w * (vv * w - 2.f * uu);
            s += (double)hsum(g);
        }
    }
    double tot = blk_reduce(s);
    if (tid == 0) err32[b * TP1 + t] = tot;
}

// Fused argmin + state update + object emit + (u,v for next step) + bookkeeping.
// LAST step emits recons = A_L + M_L * bg (affine dead-leaves identity).
template <bool FIRST, bool LAST>
__global__ void k_upd(const f4* __restrict__ temps, const f4* __restrict__ masks,
                      const f4* __restrict__ x, const f4* __restrict__ bg,
                      const double* __restrict__ err,
                      int* __restrict__ used, f4* __restrict__ A, f4* __restrict__ M,
                      f4* __restrict__ u, f4* __restrict__ v,
                      f4* __restrict__ out_obj, f4* __restrict__ out_msk,
                      f4* __restrict__ out_rec, float* __restrict__ out_ids, int l) {
    const int tid = threadIdx.x;
    const int gid = blockIdx.x * 256 + tid;      // over B*HW4 (65536), 256 blocks
    const int b = gid >> 12;
    const int p = gid & (HW4 - 1);
    __shared__ int ssel;
    if (tid < 64) {
        double best = 1e301;
        int bi = TP1;
        for (int t = tid; t < TP1; t += 64) {
            double e = err[b * TP1 + t];
            if (e < best) { best = e; bi = t; }   // ascending t per thread: < keeps first
        }
        for (int off = 32; off; off >>= 1) {
            double oe = __shfl_down(best, off);
            int    oi = __shfl_down(bi, off);
            if (oe < best || (oe == best && oi < bi)) { best = oe; bi = oi; }
        }
        if (tid == 0) ssel = bi;
    }
    __syncthreads();
    const int id = ssel;
    f4 st, sm;
    if (id == 0) {
        st = (f4){5.f, 5.f, 5.f, 5.f};
        sm = (f4){1.f, 1.f, 1.f, 1.f};
    } else {
        size_t base = ((size_t)(b * TT + id - 1)) * HW4 + p;
        st = temps[base];
        sm = masks[base];
    }
    f4 a, mp;
    if (FIRST) { a = (f4){0.f, 0.f, 0.f, 0.f}; mp = (f4){1.f, 1.f, 1.f, 1.f}; }
    else       { a = A[gid]; mp = M[gid]; }
    a = a + mp * st * sm;
    mp = mp * (1.f - sm);
    const size_t ob = ((size_t)(b * LL + l)) * HW4 + p;
    out_obj[ob] = st;
    out_msk[ob] = sm;
    if (LAST) {
        out_rec[gid] = a + mp * bg[p];
    } else {
        A[gid] = a; M[gid] = mp;
        f4 xv = x[gid];
        u[gid] = (xv - a) * mp;
        v[gid] = mp * mp;
    }
    if ((blockIdx.x & 15) == 0 && tid == 0) {      // one block per batch
        if (id != 0) used[b * TP1 + id] = 1;
        out_ids[b * LL + l] = (float)id;
    }
}

__global__ void k_uv0(const f4* __restrict__ x, f4* __restrict__ u, f4* __restrict__ v,
                      int* __restrict__ used) {
    int gid = blockIdx.x * blockDim.x + threadIdx.x;
    if (gid < BB * TP1) used[gid] = 0;
    if (gid >= BB * HW4) return;
    u[gid] = x[gid];
    v[gid] = (f4){1.f, 1.f, 1.f, 1.f};
}

static inline void launch_upd(bool first, bool last,
                              const f4* temps, const f4* masks, const f4* x, const f4* bg,
                              const double* err, int* used, f4* A, f4* M,
                              f4* u, f4* v, f4* out_obj, f4* out_msk, f4* out_rec,
                              float* out_ids, int l, hipStream_t stream) {
    if (first)
        k_upd<true, false><<<256, 256, 0, stream>>>(temps, masks, x, bg, err, used, A, M, u, v, out_obj, out_msk, out_rec, out_ids, l);
    else if (last)
        k_upd<false, true><<<256, 256, 0, stream>>>(temps, masks, x, bg, err, used, A, M, u, v, out_obj, out_msk, out_rec, out_ids, l);
    else
        k_upd<false, false><<<256, 256, 0, stream>>>(temps, masks, x, bg, err, used, A, M, u, v, out_obj, out_msk, out_rec, out_ids, l);
}

extern "C" void kernel_launch(void* const* d_in, const int* in_sizes, int n_in,
                              void* d_out, int out_size, void* d_ws, size_t ws_size,
                              hipStream_t stream) {
    const f4* x     = (const f4*)d_in[0];
    const f4* temps = (const f4*)d_in[1];
    const f4* masks = (const f4*)d_in[2];
    const f4* bg    = (const f4*)d_in[3];

    float* out      = (float*)d_out;
    f4*    out_rec  = (f4*)out;                           // B*HW
    f4*    out_obj  = (f4*)(out + 262144);                // B*L*HW
    f4*    out_msk  = (f4*)(out + 262144 + 1572864);      // B*L*HW
    float* out_ids  = out + 262144 + 2 * 1572864;         // B*L

    char* ws = (char*)d_ws;
    f4*     A     = (f4*)(ws + OFF_A);
    f4*     M     = (f4*)(ws + OFF_M);
    f4*     u     = (f4*)(ws + OFF_U);
    f4*     v     = (f4*)(ws + OFF_V);
    double* err32 = (double*)(ws + OFF_ERR32);
    double* err16 = (double*)(ws + OFF_ERR16);
    double* D     = (double*)(ws + OFF_D);
    int*    used  = (int*)(ws + OFF_USED);
    h4*     b16   = (h4*)(ws + OFF_B16);

    const bool full = (ws_size >= WS_FULL);

    if (full) {
        k_below_err0<<<dim3(TP1, BB), 256, 0, stream>>>(temps, masks, bg, x, b16, err32, used);
        for (int l = 0; l < LL; ++l) {
            launch_upd(l == 0, l == LL - 1, temps, masks, x, bg, err32, used, A, M, u, v,
                       out_obj, out_msk, out_rec, out_ids, l, stream);
            if (l < LL - 1) {
                k_err16<<<dim3(TP1, BB), 256, 0, stream>>>((const h8*)b16, u, v, used, err16, D);
                k_refine<<<dim3(TP1, BB), 256, 0, stream>>>(temps, masks, bg, u, v, err16, D, err32);
            }
        }
    } else {
        k_uv0<<<(BB * HW4 + 255) / 256, 256, 0, stream>>>(x, u, v, used);
        for (int l = 0; l < LL; ++l) {
            k_err_f32<<<dim3(TP1, BB), 256, 0, stream>>>(temps, masks, bg, u, v, used, err32);
            launch_upd(l == 0, l == LL - 1, temps, masks, x, bg, err32, used, A, M, u, v,
                       out_obj, out_msk, out_rec, out_ids, l, stream);
        }
    }
}